// Round 21
// baseline (192.418 us; speedup 1.0000x reference)
//
#include <hip/hip_runtime.h>

#define DFEAT 4096
#define NTH 512

typedef float2 cpx;

__device__ __forceinline__ cpx cmulf(cpx a, cpx b) {
  return make_float2(a.x * b.x - a.y * b.y, a.x * b.y + a.y * b.x);
}

// pad 1 cpx every 16: uniform bank spread for strided scatters
#define IDX(i) ((i) + ((i) >> 4))
#define NPAD (DFEAT + DFEAT / 16)   // 4352 cpx = 34816 B

// sin/cos in REVOLUTIONS (hardware v_sin_f32 semantics); args here in [0, 0.125)
__device__ __forceinline__ float sin_rev(float rev) {
#if __has_builtin(__builtin_amdgcn_sinf)
  return __builtin_amdgcn_sinf(rev);
#else
  return __sinf(rev * 6.28318530717958647692f);
#endif
}
__device__ __forceinline__ float cos_rev(float rev) {
#if __has_builtin(__builtin_amdgcn_cosf)
  return __builtin_amdgcn_cosf(rev);
#else
  return __cosf(rev * 6.28318530717958647692f);
#endif
}

// DFT4 with sign SGN (-1 fwd, +1 inv), in-place on 4 cpx: out[s] in slot s
template <int SGN>
__device__ __forceinline__ void dft4(cpx& p0, cpx& p1, cpx& p2, cpx& p3) {
  cpx t0 = make_float2(p0.x + p2.x, p0.y + p2.y);
  cpx t1 = make_float2(p0.x - p2.x, p0.y - p2.y);
  cpx t2 = make_float2(p1.x + p3.x, p1.y + p3.y);
  cpx t3 = make_float2(p1.x - p3.x, p1.y - p3.y);
  cpx it3 = (SGN > 0) ? make_float2(-t3.y, t3.x) : make_float2(t3.y, -t3.x);
  p0 = make_float2(t0.x + t2.x, t0.y + t2.y);
  p2 = make_float2(t0.x - t2.x, t0.y - t2.y);
  p1 = make_float2(t1.x + it3.x, t1.y + it3.y);
  p3 = make_float2(t1.x - it3.x, t1.y - it3.y);
}

// 8-pt DFT in-place: X[s] = sum_r v[r] exp(SGN 2πi rs/8), X[s] left in v[s].
// r = r1 + 2*r2: DFT4 over r2 (even/odd input sets) -> W8^{s1} on odd branch
// -> radix-2 combine. Verified: all-ones -> 8·δ; impulse@r=1 -> W8^s.
template <int SGN>
__device__ __forceinline__ void dft8(cpx v[8]) {
  cpx e0 = v[0], e1 = v[2], e2 = v[4], e3 = v[6];
  cpx o0 = v[1], o1 = v[3], o2 = v[5], o3 = v[7];
  dft4<SGN>(e0, e1, e2, e3);
  dft4<SGN>(o0, o1, o2, o3);
  const float C = 0.70710678118654752440f;
  o1 = cmulf(o1, make_float2(C, (SGN > 0) ? C : -C));
  o2 = (SGN > 0) ? make_float2(-o2.y, o2.x) : make_float2(o2.y, -o2.x);
  o3 = cmulf(o3, make_float2(-C, (SGN > 0) ? C : -C));
  v[0] = make_float2(e0.x + o0.x, e0.y + o0.y);
  v[4] = make_float2(e0.x - o0.x, e0.y - o0.y);
  v[1] = make_float2(e1.x + o1.x, e1.y + o1.y);
  v[5] = make_float2(e1.x - o1.x, e1.y - o1.y);
  v[2] = make_float2(e2.x + o2.x, e2.y + o2.y);
  v[6] = make_float2(e2.x - o2.x, e2.y - o2.y);
  v[3] = make_float2(e3.x + o3.x, e3.y + o3.y);
  v[7] = make_float2(e3.x - o3.x, e3.y - o3.y);
}

// v[r] *= w^r, w = exp(SGN 2πi rev). Serial chain: 2 live values only
// (R19 lesson: wide powering spills at a tight VGPR budget).
template <int SGN>
__device__ __forceinline__ void twiddle8(cpx v[8], float rev) {
  float s = sin_rev(rev), c = cos_rev(rev);
  cpx w1 = make_float2(c, (SGN > 0) ? s : -s);
  cpx w = w1;
  v[1] = cmulf(v[1], w);
#pragma unroll
  for (int r = 2; r < 8; ++r) { w = cmulf(w, w1); v[r] = cmulf(v[r], w); }
}

// 4096-pt FFT, radix-8 Stockham, 4 stages, 512 threads, 8 cpx/thread.
// Entry: v[r] = input at position j+512r. Exit: v[s] = output at position j+512s.
// Stages 0 and 3 register-resident; one in-place LDS buffer, 6 barriers.
// Stage Ns: write dst[m*8Ns + k + Ns*s], m=j>>log2(Ns), k=j&(Ns-1) — same
// Stockham recurrence HW-verified at radix-4 (R12) and radix-16 (R14+).
template <int SGN>
__device__ __forceinline__ void fft4096_r8(cpx v[8], cpx* B, int j) {
  dft8<SGN>(v);                                   // st0 (Ns=1, no twiddle)
  __syncthreads();                                // protect prior consumers of B
#pragma unroll
  for (int s = 0; s < 8; ++s) B[IDX(8 * j + s)] = v[s];
  __syncthreads();
#pragma unroll
  for (int r = 0; r < 8; ++r) v[r] = B[IDX(j + 512 * r)];
  __syncthreads();                                // reads done before next writes
  twiddle8<SGN>(v, (float)(j & 7) * (1.0f / 64.0f));
  dft8<SGN>(v);                                   // st1 (Ns=8)
#pragma unroll
  for (int s = 0; s < 8; ++s) B[IDX((j >> 3) * 64 + (j & 7) + 8 * s)] = v[s];
  __syncthreads();
#pragma unroll
  for (int r = 0; r < 8; ++r) v[r] = B[IDX(j + 512 * r)];
  __syncthreads();                                // reads done before next writes
  twiddle8<SGN>(v, (float)(j & 63) * (1.0f / 512.0f));
  dft8<SGN>(v);                                   // st2 (Ns=64)
#pragma unroll
  for (int s = 0; s < 8; ++s) B[IDX((j >> 6) * 512 + (j & 63) + 64 * s)] = v[s];
  __syncthreads();
#pragma unroll
  for (int r = 0; r < 8; ++r) v[r] = B[IDX(j + 512 * r)];
  twiddle8<SGN>(v, (float)j * (1.0f / 4096.0f));
  dft8<SGN>(v);                                   // st3 (Ns=512) -> natural order
  // caller's next entry-sync protects these final reads
}

// Ghat[r] = FFT(g[r]) / 4096
__global__ __launch_bounds__(NTH, 1) void ghat_kernel(const float* __restrict__ g,
                                                      cpx* __restrict__ Ghat) {
  __shared__ cpx B[NPAD];
  const int rr = blockIdx.x;
  const int j = threadIdx.x;
  cpx v[8];
#pragma unroll
  for (int r = 0; r < 8; ++r) {
    int pos = j + 512 * r;
    v[r] = make_float2(g[rr * DFEAT + pos], 0.0f);
  }
  fft4096_r8<-1>(v, B, j);
  const float inv = 1.0f / 4096.0f;
#pragma unroll
  for (int s = 0; s < 8; ++s) {
    int pos = j + 512 * s;
    Ghat[rr * DFEAT + pos] = make_float2(v[s].x * inv, v[s].y * inv);
  }
}

// One block = one row PAIR (two-for-one):
//   w = x1*psi + i*x2*psi ; W = FFT(w), parked in THREAD-PRIVATE LDS slots
//   for r: z = IFFT(W*Ghat_r); a1 += Re(z)*omega_r; a2 += Im(z)*omega_r
// 512 threads / 8 cpx per thread: live set ~70 VGPR -> 2 blocks/CU with
// 16 waves/CU (4/SIMD), double R20's TLP at the same LDS budget.
__global__ __launch_bounds__(NTH, 2) void fftconv_kernel(
    const float* __restrict__ x, const float* __restrict__ psi,
    const float* __restrict__ omega, const float* __restrict__ bias,
    const cpx* __restrict__ Ghat, float* __restrict__ out) {
  __shared__ cpx B[NPAD];
  __shared__ cpx Wl[NPAD];
  const int p = blockIdx.x;
  const int j = threadIdx.x;
  const float* x1 = x + ((size_t)(2 * p)) * DFEAT;
  const float* x2 = x1 + DFEAT;

  cpx v[8];
#pragma unroll
  for (int r = 0; r < 8; ++r) {
    int pos = j + 512 * r;
    float ps = psi[pos];
    v[r] = make_float2(x1[pos] * ps, x2[pos] * ps);
  }
  fft4096_r8<-1>(v, B, j);

  // park W in thread-private LDS slots (no barriers needed: self-only access)
#pragma unroll
  for (int s = 0; s < 8; ++s) Wl[IDX(j + 512 * s)] = v[s];

  float a1[8], a2[8];
#pragma unroll
  for (int s = 0; s < 8; ++s) { a1[s] = 0.0f; a2[s] = 0.0f; }

  for (int r = 0; r < 3; ++r) {
#pragma unroll
    for (int q = 0; q < 8; ++q) {
      int pos = j + 512 * q;
      v[q] = cmulf(Wl[IDX(pos)], Ghat[r * DFEAT + pos]);
    }
    fft4096_r8<1>(v, B, j);
#pragma unroll
    for (int s = 0; s < 8; ++s) {
      int pos = j + 512 * s;
      float om = omega[r * DFEAT + pos];
      a1[s] += v[s].x * om;
      a2[s] += v[s].y * om;
    }
  }

  float* o1 = out + ((size_t)(2 * p)) * DFEAT;
#pragma unroll
  for (int s = 0; s < 8; ++s) {
    int pos = j + 512 * s;
    float b = bias[pos];
    o1[pos] = a1[s] + b;
    o1[DFEAT + pos] = a2[s] + b;
  }
}

extern "C" void kernel_launch(void* const* d_in, const int* in_sizes, int n_in,
                              void* d_out, int out_size, void* d_ws, size_t ws_size,
                              hipStream_t stream) {
  const float* x     = (const float*)d_in[0];
  const float* psi   = (const float*)d_in[1];
  const float* omega = (const float*)d_in[2];
  const float* g     = (const float*)d_in[3];
  const float* bias  = (const float*)d_in[4];

  const int M = in_sizes[0] / DFEAT;   // 8192 rows

  cpx* Ghat = (cpx*)d_ws;              // 3 * 4096 * 8B = 96 KB

  ghat_kernel<<<3, NTH, 0, stream>>>(g, Ghat);
  fftconv_kernel<<<M / 2, NTH, 0, stream>>>(x, psi, omega, bias, Ghat,
                                            (float*)d_out);
}